// Round 1
// baseline (691.724 us; speedup 1.0000x reference)
//
#include <hip/hip_runtime.h>
#include <hip/hip_bf16.h>

// 2-layer LSTM (H=32, T=512, I=1) + FC(1) + ReLU, fused in one kernel.
// MFMA 16x16x32 bf16: M=gate-chunk (weights, A), N=batch (h, B), K=32=H.
// Permuted weight packing makes cell update lane-local and h_new land
// directly in B-fragment layout (no LDS, no barriers, single wave/block).

typedef __attribute__((ext_vector_type(8))) short bf16x8;
typedef __attribute__((ext_vector_type(4))) float f32x4;

#define HID 32
#define SEQ 512
#define NBW 4   // batches per wave (of 16 MFMA N-cols; 4..15 are don't-care)

__device__ __forceinline__ float fexp2(float x) { return __builtin_amdgcn_exp2f(x); }
__device__ __forceinline__ float frcpf(float x) { return __builtin_amdgcn_rcpf(x); }
// sigmoid(x) = 1/(1+2^(-x*log2e))
__device__ __forceinline__ float fsigmoid(float x) { return frcpf(1.0f + fexp2(-1.442695041f * x)); }
// tanh(x) = 1 - 2/(2^(2x*log2e)+1)
__device__ __forceinline__ float ftanhf(float x) { float e = fexp2(2.885390082f * x); return 1.0f - 2.0f * frcpf(e + 1.0f); }
// float -> bf16 bits, RNE (inputs are finite/bounded here)
__device__ __forceinline__ short f2bf(float f) {
  unsigned u = __builtin_bit_cast(unsigned, f);
  u = (u + 0x7fffu + ((u >> 16) & 1u)) >> 16;
  return (short)u;
}

__global__ __launch_bounds__(64, 1) void lstm2_fused_kernel(
    const float* __restrict__ x,
    const float* __restrict__ Wih0, const float* __restrict__ Whh0,
    const float* __restrict__ bih0, const float* __restrict__ bhh0,
    const float* __restrict__ Wih1, const float* __restrict__ Whh1,
    const float* __restrict__ bih1, const float* __restrict__ bhh1,
    const float* __restrict__ Wfc, const float* __restrict__ bfc,
    float* __restrict__ out)
{
  const int l   = threadIdx.x;
  const int m   = l >> 4;      // k-group (A/B fragment k = 8m + j)
  const int col = l & 15;      // MFMA N col (batch slot); also A source row
  const int batch = blockIdx.x * NBW + (col & (NBW - 1)); // cols >= NBW duplicate

  // ---- weight fragments (A operands), gate-row permutation:
  //      g(c, rho) = (c>>1)*32 + 8*(rho>>2) + 4*(c&1) + (rho&3)
  bf16x8 whh0f[8], wih1f[8], whh1f[8];
  float wih0p[32], bias0p[32], bias1p[32];
  #pragma unroll
  for (int c = 0; c < 8; ++c) {
    const int tau = c >> 1, kh = c & 1;
    const int ga = tau * 32 + ((col >> 2) << 3) + (kh << 2) + (col & 3); // A row rho = col
    #pragma unroll
    for (int j = 0; j < 8; ++j) {
      const int k = m * 8 + j;
      whh0f[c][j] = f2bf(Whh0[ga * HID + k]);
      wih1f[c][j] = f2bf(Wih1[ga * HID + k]);
      whh1f[c][j] = f2bf(Whh1[ga * HID + k]);
    }
    // D-layout per-lane constants: D row = 4*m + r
    #pragma unroll
    for (int r = 0; r < 4; ++r) {
      const int gd = tau * 32 + (m << 3) + (kh << 2) + r;
      wih0p[c * 4 + r]  = Wih0[gd];
      bias0p[c * 4 + r] = bih0[gd] + bhh0[gd];
      bias1p[c * 4 + r] = bih1[gd] + bhh1[gd];
    }
  }

  bf16x8 h0f, h1f;
  float c0v[8], c1v[8], h1fp[8];
  #pragma unroll
  for (int j = 0; j < 8; ++j) { h0f[j] = 0; h1f[j] = 0; c0v[j] = 0.f; c1v[j] = 0.f; h1fp[j] = 0.f; }

  const float* xb = x + (size_t)batch * SEQ;

  for (int t4 = 0; t4 < SEQ / 4; ++t4) {
    const float4 xv = *reinterpret_cast<const float4*>(xb + t4 * 4);
    #pragma unroll
    for (int u = 0; u < 4; ++u) {
      const float xt = (u == 0) ? xv.x : (u == 1) ? xv.y : (u == 2) ? xv.z : xv.w;

      // ---------- layer 0 ----------
      f32x4 a[8];
      #pragma unroll
      for (int c = 0; c < 8; ++c) {
        #pragma unroll
        for (int r = 0; r < 4; ++r)
          a[c][r] = bias0p[c * 4 + r] + wih0p[c * 4 + r] * xt;
      }
      #pragma unroll
      for (int c = 0; c < 8; ++c)
        a[c] = __builtin_amdgcn_mfma_f32_16x16x32_bf16(whh0f[c], h0f, a[c], 0, 0, 0);
      #pragma unroll
      for (int j = 0; j < 8; ++j) {   // hidden k = 8m + j, lane-local i/f/g/o
        const int ch = j >> 2, r = j & 3;
        const float ig = fsigmoid(a[0 + ch][r]);
        const float fg = fsigmoid(a[2 + ch][r]);
        const float gg = ftanhf  (a[4 + ch][r]);
        const float og = fsigmoid(a[6 + ch][r]);
        c0v[j] = fg * c0v[j] + ig * gg;
        h0f[j] = f2bf(og * ftanhf(c0v[j]));   // lands in B-frag slot directly
      }

      // ---------- layer 1 ----------
      #pragma unroll
      for (int c = 0; c < 8; ++c) {
        #pragma unroll
        for (int r = 0; r < 4; ++r)
          a[c][r] = bias1p[c * 4 + r];
      }
      #pragma unroll
      for (int c = 0; c < 8; ++c)
        a[c] = __builtin_amdgcn_mfma_f32_16x16x32_bf16(wih1f[c], h0f, a[c], 0, 0, 0);
      #pragma unroll
      for (int c = 0; c < 8; ++c)
        a[c] = __builtin_amdgcn_mfma_f32_16x16x32_bf16(whh1f[c], h1f, a[c], 0, 0, 0);
      #pragma unroll
      for (int j = 0; j < 8; ++j) {
        const int ch = j >> 2, r = j & 3;
        const float ig = fsigmoid(a[0 + ch][r]);
        const float fg = fsigmoid(a[2 + ch][r]);
        const float gg = ftanhf  (a[4 + ch][r]);
        const float og = fsigmoid(a[6 + ch][r]);
        c1v[j] = fg * c1v[j] + ig * gg;
        const float h = og * ftanhf(c1v[j]);
        h1fp[j] = h;
        h1f[j] = f2bf(h);
      }
    }
  }

  // ---- final FC + ReLU: out[b] = relu(sum_k h1[k]*Wfc[k] + bfc) ----
  float part = 0.f;
  #pragma unroll
  for (int j = 0; j < 8; ++j) part += h1fp[j] * Wfc[m * 8 + j];
  part += __shfl_xor(part, 16);
  part += __shfl_xor(part, 32);
  if (m == 0 && col < NBW) {
    const float o = part + bfc[0];
    out[batch] = o > 0.f ? o : 0.f;
  }
}

extern "C" void kernel_launch(void* const* d_in, const int* in_sizes, int n_in,
                              void* d_out, int out_size, void* d_ws, size_t ws_size,
                              hipStream_t stream) {
  const float* x    = (const float*)d_in[0];
  const float* Wih0 = (const float*)d_in[1];
  const float* Whh0 = (const float*)d_in[2];
  const float* bih0 = (const float*)d_in[3];
  const float* bhh0 = (const float*)d_in[4];
  const float* Wih1 = (const float*)d_in[5];
  const float* Whh1 = (const float*)d_in[6];
  const float* bih1 = (const float*)d_in[7];
  const float* bhh1 = (const float*)d_in[8];
  const float* Wfc  = (const float*)d_in[9];
  const float* bfc  = (const float*)d_in[10];

  const int B = 4096;
  const int grid = B / NBW;   // 1024 single-wave blocks -> ~1 wave/SIMD chip-wide
  lstm2_fused_kernel<<<grid, 64, 0, stream>>>(
      x, Wih0, Whh0, bih0, bhh0, Wih1, Whh1, bih1, bhh1, Wfc, bfc,
      (float*)d_out);
}

// Round 2
// 320.237 us; speedup vs baseline: 2.1600x; 2.1600x over previous
//
#include <hip/hip_runtime.h>
#include <hip/hip_bf16.h>

// 2-layer LSTM (H=32, T=512, I=1) + FC(1) + ReLU, fused.
// MFMA 16x16x32 bf16, NBW=4 batches/wave. The 4 replicated col-groups split
// the elementwise work: lane (m, q, s) owns hidden units u = 8m+2q+{0,1} of
// batch s. Gate extraction via cndmask selects (fixed register slots);
// h reassembled into B-fragment layout via v_cvt_pk_bf16_f32 + 4 ds_swizzle.
// Activation scales pre-folded into weight rows; MFMA C-in = const zero.

typedef __attribute__((ext_vector_type(8))) short bf16x8;
typedef __attribute__((ext_vector_type(4))) float f32x4;
typedef __attribute__((ext_vector_type(4))) int   i32x4;

#define HID 32
#define SEQ 512
#define NBW 4
#define L2E 1.4426950408889634f

static __device__ __forceinline__ float fexp2(float x){ return __builtin_amdgcn_exp2f(x); }
static __device__ __forceinline__ float frcp (float x){ return __builtin_amdgcn_rcpf(x); }
static __device__ __forceinline__ short f2bf(float f){
  unsigned u = __builtin_bit_cast(unsigned, f);
  u = (u + 0x7fffu + ((u >> 16) & 1u)) >> 16;
  return (short)u;
}

// select gate value for (tau, jj) from D-regs: slot (c = 2tau + khb, r = 2rb + jj)
#define SEL(Atab, tau, jj) \
  ( khb ? ( rb ? Atab[2*(tau)+1][2+(jj)] : Atab[2*(tau)+1][(jj)] ) \
        : ( rb ? Atab[2*(tau)  ][2+(jj)] : Atab[2*(tau)  ][(jj)] ) )

__global__ __launch_bounds__(64, 1) void lstm2_fused_kernel(
    const float* __restrict__ x,
    const float* __restrict__ Wih0, const float* __restrict__ Whh0,
    const float* __restrict__ bih0, const float* __restrict__ bhh0,
    const float* __restrict__ Wih1, const float* __restrict__ Whh1,
    const float* __restrict__ bih1, const float* __restrict__ bhh1,
    const float* __restrict__ Wfc, const float* __restrict__ bfc,
    float* __restrict__ out)
{
  const int l   = threadIdx.x;
  const int m   = l >> 4;          // A/B fragment k-group
  const int col = l & 15;          // MFMA N col
  const int q   = col >> 2;        // replication group -> owns units 8m+2q+{0,1}
  const int s   = col & 3;         // batch slot
  const int batch = blockIdx.x * NBW + s;
  const bool khb = ((q >> 1) & 1) != 0;   // chunk-half select bit
  const bool rb  = (q & 1) != 0;          // r select bit

  // ---- weight fragments (A operands), rows pre-scaled by activation scale:
  //      i,f,o rows: -log2e (sigmoid);  g rows: +2*log2e (tanh)
  bf16x8 whh0f[8], wih1f[8], whh1f[8];
  #pragma unroll
  for (int c = 0; c < 8; ++c) {
    const int tau = c >> 1, kh = c & 1;
    const float sc = (tau == 2) ? (2.0f * L2E) : (-L2E);
    const int ga = tau * 32 + ((col >> 2) << 3) + (kh << 2) + (col & 3);
    #pragma unroll
    for (int j = 0; j < 8; ++j) {
      const int k = m * 8 + j;
      whh0f[c][j] = f2bf(sc * Whh0[ga * HID + k]);
      wih1f[c][j] = f2bf(sc * Wih1[ga * HID + k]);
      whh1f[c][j] = f2bf(sc * Whh1[ga * HID + k]);
    }
  }

  // ---- per-lane activation constants for its 2 units u = 8m+2q+jj
  float c0x[4][2], w0x[4][2], c1x[4][2];
  #pragma unroll
  for (int tau = 0; tau < 4; ++tau) {
    const float sc = (tau == 2) ? (2.0f * L2E) : (-L2E);
    #pragma unroll
    for (int jj = 0; jj < 2; ++jj) {
      const int u = 8 * m + 2 * q + jj;
      const int g = tau * 32 + u;
      c0x[tau][jj] = sc * (bih0[g] + bhh0[g]);
      w0x[tau][jj] = sc * Wih0[g];
      c1x[tau][jj] = sc * (bih1[g] + bhh1[g]);
    }
  }
  const float wfcA = Wfc[8 * m + 2 * q];
  const float wfcB = Wfc[8 * m + 2 * q + 1];
  const float bfc0 = bfc[0];

  const f32x4 z4 = {0.f, 0.f, 0.f, 0.f};
  bf16x8 h0f = {}, h1f = {};
  float c0v[2] = {0.f, 0.f}, c1v[2] = {0.f, 0.f};
  float h1n0 = 0.f, h1n1 = 0.f;

  const float* xb = x + (size_t)batch * SEQ;

  for (int t4 = 0; t4 < SEQ / 4; ++t4) {
    const float4 xv = *reinterpret_cast<const float4*>(xb + t4 * 4);
    #pragma unroll
    for (int uu = 0; uu < 4; ++uu) {
      const float xt = (uu == 0) ? xv.x : (uu == 1) ? xv.y : (uu == 2) ? xv.z : xv.w;

      // ---------- layer 0: D = Whh0*h0 (fresh accumulator) ----------
      f32x4 A[8];
      #pragma unroll
      for (int c = 0; c < 8; ++c)
        A[c] = __builtin_amdgcn_mfma_f32_16x16x32_bf16(whh0f[c], h0f, z4, 0, 0, 0);

      float h0n0, h0n1;
      #pragma unroll
      for (int jj = 0; jj < 2; ++jj) {
        const float gi = SEL(A, 0, jj) + fmaf(w0x[0][jj], xt, c0x[0][jj]);
        const float gf = SEL(A, 1, jj) + fmaf(w0x[1][jj], xt, c0x[1][jj]);
        const float gg = SEL(A, 2, jj) + fmaf(w0x[2][jj], xt, c0x[2][jj]);
        const float go = SEL(A, 3, jj) + fmaf(w0x[3][jj], xt, c0x[3][jj]);
        const float iv = frcp(1.f + fexp2(gi));          // sigmoid (scale folded)
        const float fv = frcp(1.f + fexp2(gf));
        const float gv = fmaf(frcp(1.f + fexp2(gg)), -2.f, 1.f);  // tanh
        const float ov = frcp(1.f + fexp2(go));
        c0v[jj] = fmaf(fv, c0v[jj], iv * gv);
        const float th = fmaf(frcp(1.f + fexp2(c0v[jj] * (2.f * L2E))), -2.f, 1.f);
        const float hn = ov * th;
        if (jj == 0) h0n0 = hn; else h0n1 = hn;
      }
      int pk0;
      asm("v_cvt_pk_bf16_f32 %0, %1, %2" : "=v"(pk0) : "v"(h0n0), "v"(h0n1));
      i32x4 hp0;
      hp0[0] = __builtin_amdgcn_ds_swizzle(pk0, 0x013);  // src q'=0
      hp0[1] = __builtin_amdgcn_ds_swizzle(pk0, 0x093);  // q'=1
      hp0[2] = __builtin_amdgcn_ds_swizzle(pk0, 0x113);  // q'=2
      hp0[3] = __builtin_amdgcn_ds_swizzle(pk0, 0x193);  // q'=3
      h0f = __builtin_bit_cast(bf16x8, hp0);

      // ---------- layer 1: D = Wih1*h0_new + Whh1*h1_prev ----------
      #pragma unroll
      for (int c = 0; c < 8; ++c)
        A[c] = __builtin_amdgcn_mfma_f32_16x16x32_bf16(wih1f[c], h0f, z4, 0, 0, 0);
      #pragma unroll
      for (int c = 0; c < 8; ++c)
        A[c] = __builtin_amdgcn_mfma_f32_16x16x32_bf16(whh1f[c], h1f, A[c], 0, 0, 0);

      #pragma unroll
      for (int jj = 0; jj < 2; ++jj) {
        const float gi = SEL(A, 0, jj) + c1x[0][jj];
        const float gf = SEL(A, 1, jj) + c1x[1][jj];
        const float gg = SEL(A, 2, jj) + c1x[2][jj];
        const float go = SEL(A, 3, jj) + c1x[3][jj];
        const float iv = frcp(1.f + fexp2(gi));
        const float fv = frcp(1.f + fexp2(gf));
        const float gv = fmaf(frcp(1.f + fexp2(gg)), -2.f, 1.f);
        const float ov = frcp(1.f + fexp2(go));
        c1v[jj] = fmaf(fv, c1v[jj], iv * gv);
        const float th = fmaf(frcp(1.f + fexp2(c1v[jj] * (2.f * L2E))), -2.f, 1.f);
        const float hn = ov * th;
        if (jj == 0) h1n0 = hn; else h1n1 = hn;
      }
      int pk1;
      asm("v_cvt_pk_bf16_f32 %0, %1, %2" : "=v"(pk1) : "v"(h1n0), "v"(h1n1));
      i32x4 hp1;
      hp1[0] = __builtin_amdgcn_ds_swizzle(pk1, 0x013);
      hp1[1] = __builtin_amdgcn_ds_swizzle(pk1, 0x093);
      hp1[2] = __builtin_amdgcn_ds_swizzle(pk1, 0x113);
      hp1[3] = __builtin_amdgcn_ds_swizzle(pk1, 0x193);
      h1f = __builtin_bit_cast(bf16x8, hp1);
    }
  }

  // ---- FC + ReLU: out[b] = relu(sum_u h1[u]*Wfc[u] + bfc) ----
  float part = h1n0 * wfcA + h1n1 * wfcB;
  part += __shfl_xor(part, 4);
  part += __shfl_xor(part, 8);
  part += __shfl_xor(part, 16);
  part += __shfl_xor(part, 32);
  if (l < 4) {
    const float o = part + bfc0;
    out[blockIdx.x * NBW + l] = o > 0.f ? o : 0.f;
  }
}

extern "C" void kernel_launch(void* const* d_in, const int* in_sizes, int n_in,
                              void* d_out, int out_size, void* d_ws, size_t ws_size,
                              hipStream_t stream) {
  const float* x    = (const float*)d_in[0];
  const float* Wih0 = (const float*)d_in[1];
  const float* Whh0 = (const float*)d_in[2];
  const float* bih0 = (const float*)d_in[3];
  const float* bhh0 = (const float*)d_in[4];
  const float* Wih1 = (const float*)d_in[5];
  const float* Whh1 = (const float*)d_in[6];
  const float* bih1 = (const float*)d_in[7];
  const float* bhh1 = (const float*)d_in[8];
  const float* Wfc  = (const float*)d_in[9];
  const float* bfc  = (const float*)d_in[10];

  const int B = 4096;
  const int grid = B / NBW;   // 1024 single-wave blocks -> 1 wave/SIMD chip-wide
  lstm2_fused_kernel<<<grid, 64, 0, stream>>>(
      x, Wih0, Whh0, bih0, bhh0, Wih1, Whh1, bih1, bhh1, Wfc, bfc,
      (float*)d_out);
}